// Round 1
// baseline (2824.682 us; speedup 1.0000x reference)
//
#include <hip/hip_runtime.h>

#define NDIM 128

// ---------------------------------------------------------------------------
// Kernel 1: h = x @ W   (x: [N,128] f32, W: [128,128] f32, h: [N,128] f32)
// W staged in LDS (64 KB). Each block: 256 threads = 4 waves, 16 rows/block
// (4 rows per wave). Each lane computes 2 adjacent output columns (float2),
// x values read from global as wave-uniform broadcast loads (L1-resident).
// ---------------------------------------------------------------------------
__global__ __launch_bounds__(256) void gemm128(const float* __restrict__ x,
                                               const float* __restrict__ W,
                                               float* __restrict__ h,
                                               int n_nodes) {
    __shared__ float Wl[NDIM * NDIM];  // 64 KB
    const int tid = threadIdx.x;

    // Cooperative load of W: 16384 floats = 4096 float4 / 256 threads = 16 each
    const float4* W4 = (const float4*)W;
    float4* Wl4 = (float4*)Wl;
#pragma unroll
    for (int i = 0; i < 16; ++i) {
        Wl4[tid + i * 256] = W4[tid + i * 256];
    }
    __syncthreads();

    const int wave = tid >> 6;
    const int lane = tid & 63;
    const int c = lane * 2;                       // 64 lanes * 2 cols = 128
    const int row0 = blockIdx.x * 16 + wave * 4;  // 4 rows per wave
    if (row0 >= n_nodes) return;                  // N % 16 == 0 in practice

    const float* xr = x + (size_t)row0 * NDIM;

    float2 acc[4];
#pragma unroll
    for (int r = 0; r < 4; ++r) { acc[r].x = 0.f; acc[r].y = 0.f; }

    for (int k = 0; k < NDIM; k += 4) {
        float4 xv[4];
#pragma unroll
        for (int r = 0; r < 4; ++r) {
            xv[r] = *(const float4*)(xr + (size_t)r * NDIM + k);  // wave-uniform broadcast
        }
        float2 wv[4];
#pragma unroll
        for (int j = 0; j < 4; ++j) {
            wv[j] = *(const float2*)(Wl + (k + j) * NDIM + c);
        }
#pragma unroll
        for (int r = 0; r < 4; ++r) {
            const float* xs = (const float*)&xv[r];
#pragma unroll
            for (int j = 0; j < 4; ++j) {
                acc[r].x = fmaf(xs[j], wv[j].x, acc[r].x);
                acc[r].y = fmaf(xs[j], wv[j].y, acc[r].y);
            }
        }
    }

#pragma unroll
    for (int r = 0; r < 4; ++r) {
        *(float2*)(h + (size_t)(row0 + r) * NDIM + c) = acc[r];
    }
}

// ---------------------------------------------------------------------------
// Kernel 2: scatter-add  agg[dst[e]] += h[src[e]]  (agg lives in d_out)
// 32 lanes per edge, each lane handles 4 consecutive floats (float4 gather,
// 4x global_atomic_add_f32, result unused -> no-return fast form).
// ---------------------------------------------------------------------------
__global__ __launch_bounds__(256) void scatter_add(const float* __restrict__ h,
                                                   const int* __restrict__ src,
                                                   const int* __restrict__ dst,
                                                   float* __restrict__ agg,
                                                   int n_edges) {
    const int gid = blockIdx.x * 256 + threadIdx.x;
    const int e = gid >> 5;
    if (e >= n_edges) return;
    const int q = (gid & 31) * 4;

    const int s = src[e];   // broadcast across the 32 lanes of this edge
    const int d = dst[e];

    float4 v = *(const float4*)(h + (size_t)s * NDIM + q);
    float* ap = agg + (size_t)d * NDIM + q;
    atomicAdd(ap + 0, v.x);
    atomicAdd(ap + 1, v.y);
    atomicAdd(ap + 2, v.z);
    atomicAdd(ap + 3, v.w);
}

// ---------------------------------------------------------------------------
// Kernel 3 (in-place): out = x + relu(out + b)
// ---------------------------------------------------------------------------
__global__ __launch_bounds__(256) void finalize(const float* __restrict__ x,
                                                const float* __restrict__ b,
                                                float* __restrict__ out,
                                                int n_vec4) {
    const int i = blockIdx.x * 256 + threadIdx.x;
    if (i >= n_vec4) return;

    float4 xv = ((const float4*)x)[i];
    float4 av = ((float4*)out)[i];
    const int dcol = (i * 4) & (NDIM - 1);
    float4 bv = *(const float4*)(b + dcol);

    float4 r;
    r.x = xv.x + fmaxf(av.x + bv.x, 0.f);
    r.y = xv.y + fmaxf(av.y + bv.y, 0.f);
    r.z = xv.z + fmaxf(av.z + bv.z, 0.f);
    r.w = xv.w + fmaxf(av.w + bv.w, 0.f);
    ((float4*)out)[i] = r;
}

extern "C" void kernel_launch(void* const* d_in, const int* in_sizes, int n_in,
                              void* d_out, int out_size, void* d_ws, size_t ws_size,
                              hipStream_t stream) {
    const float* x    = (const float*)d_in[0];
    const int*   esrc = (const int*)d_in[1];
    const int*   edst = (const int*)d_in[2];
    const float* W    = (const float*)d_in[3];
    const float* b    = (const float*)d_in[4];
    float* out = (float*)d_out;

    const int n_nodes = in_sizes[0] / NDIM;
    const int n_edges = in_sizes[1];

    float* h = (float*)d_ws;  // N*128 f32 = 51.2 MB scratch

    // agg accumulates directly in d_out; zero it every call (deterministic).
    hipMemsetAsync(d_out, 0, (size_t)out_size * sizeof(float), stream);

    gemm128<<<(n_nodes + 15) / 16, 256, 0, stream>>>(x, W, h, n_nodes);

    const long long scatter_threads = (long long)n_edges * 32;
    const int scatter_blocks = (int)((scatter_threads + 255) / 256);
    scatter_add<<<scatter_blocks, 256, 0, stream>>>(h, esrc, edst, out, n_edges);

    const int n_vec4 = n_nodes * NDIM / 4;
    finalize<<<(n_vec4 + 255) / 256, 256, 0, stream>>>(x, b, out, n_vec4);
}

// Round 2
// 440.217 us; speedup vs baseline: 6.4166x; 6.4166x over previous
//
#include <hip/hip_runtime.h>

#define NDIM 128

// ---------------------------------------------------------------------------
// Kernel 1: h = x @ W   (x: [N,128] f32, W: [128,128] f32, h: [N,128] f32)
// W staged in LDS (64 KB). 256 threads = 4 waves; 4 rows/wave; lane owns 2 cols.
// ---------------------------------------------------------------------------
__global__ __launch_bounds__(256) void gemm128(const float* __restrict__ x,
                                               const float* __restrict__ W,
                                               float* __restrict__ h,
                                               int n_nodes) {
    __shared__ float Wl[NDIM * NDIM];  // 64 KB
    const int tid = threadIdx.x;

    const float4* W4 = (const float4*)W;
    float4* Wl4 = (float4*)Wl;
#pragma unroll
    for (int i = 0; i < 16; ++i) {
        Wl4[tid + i * 256] = W4[tid + i * 256];
    }
    __syncthreads();

    const int wave = tid >> 6;
    const int lane = tid & 63;
    const int c = lane * 2;
    const int row0 = blockIdx.x * 16 + wave * 4;
    if (row0 >= n_nodes) return;

    const float* xr = x + (size_t)row0 * NDIM;

    float2 acc[4];
#pragma unroll
    for (int r = 0; r < 4; ++r) { acc[r].x = 0.f; acc[r].y = 0.f; }

    for (int k = 0; k < NDIM; k += 4) {
        float4 xv[4];
#pragma unroll
        for (int r = 0; r < 4; ++r) {
            xv[r] = *(const float4*)(xr + (size_t)r * NDIM + k);
        }
        float2 wv[4];
#pragma unroll
        for (int j = 0; j < 4; ++j) {
            wv[j] = *(const float2*)(Wl + (k + j) * NDIM + c);
        }
#pragma unroll
        for (int r = 0; r < 4; ++r) {
            const float* xs = (const float*)&xv[r];
#pragma unroll
            for (int j = 0; j < 4; ++j) {
                acc[r].x = fmaf(xs[j], wv[j].x, acc[r].x);
                acc[r].y = fmaf(xs[j], wv[j].y, acc[r].y);
            }
        }
    }

#pragma unroll
    for (int r = 0; r < 4; ++r) {
        *(float2*)(h + (size_t)(row0 + r) * NDIM + c) = acc[r];
    }
}

// ---------------------------------------------------------------------------
// CSR construction: histogram -> chunked exclusive scan -> bucket fill
// ---------------------------------------------------------------------------
__global__ __launch_bounds__(256) void hist_dst(const int* __restrict__ dst,
                                                int* __restrict__ deg,
                                                int n_edges) {
    const int e = blockIdx.x * 256 + threadIdx.x;
    if (e >= n_edges) return;
    atomicAdd(&deg[dst[e]], 1);
}

// Per-chunk (1024 elems) exclusive scan; block totals to partials.
__global__ __launch_bounds__(256) void scan_chunks(const int* __restrict__ deg,
                                                   int* __restrict__ offs,
                                                   int* __restrict__ partials,
                                                   int n) {
    __shared__ int sums[256];
    const int t = threadIdx.x;
    const int base = blockIdx.x * 1024;

    int v[4];
    int tot = 0;
#pragma unroll
    for (int j = 0; j < 4; ++j) {
        const int idx = base + t * 4 + j;
        v[j] = (idx < n) ? deg[idx] : 0;
        tot += v[j];
    }
    sums[t] = tot;
    __syncthreads();

    // Hillis-Steele inclusive scan over 256 thread-sums
    for (int off = 1; off < 256; off <<= 1) {
        const int tmp = (t >= off) ? sums[t - off] : 0;
        __syncthreads();
        sums[t] += tmp;
        __syncthreads();
    }

    int run = (t > 0) ? sums[t - 1] : 0;
#pragma unroll
    for (int j = 0; j < 4; ++j) {
        const int idx = base + t * 4 + j;
        if (idx < n) offs[idx] = run;
        run += v[j];
    }
    if (t == 255) partials[blockIdx.x] = sums[255];
}

// Serial exclusive scan of chunk totals (~98 elems; negligible).
__global__ void scan_partials(int* partials, int nchunks) {
    if (threadIdx.x == 0 && blockIdx.x == 0) {
        int run = 0;
        for (int i = 0; i < nchunks; ++i) {
            const int v = partials[i];
            partials[i] = run;
            run += v;
        }
    }
}

__global__ __launch_bounds__(256) void add_base(int* __restrict__ offs,
                                                const int* __restrict__ partials,
                                                int* __restrict__ cursor,
                                                int n) {
    const int i = blockIdx.x * 256 + threadIdx.x;
    if (i >= n) return;
    const int o = offs[i] + partials[i >> 10];
    offs[i] = o;
    cursor[i] = o;
}

__global__ __launch_bounds__(256) void bucket_fill(const int* __restrict__ src,
                                                   const int* __restrict__ dst,
                                                   int* __restrict__ cursor,
                                                   int* __restrict__ srcsorted,
                                                   int n_edges) {
    const int e = blockIdx.x * 256 + threadIdx.x;
    if (e >= n_edges) return;
    const int pos = atomicAdd(&cursor[dst[e]], 1);
    srcsorted[pos] = src[e];
}

// ---------------------------------------------------------------------------
// Gather + epilogue: one wave per node; lane owns 2 cols (float2).
// out[n] = x[n] + relu(sum_{e in CSR[n]} h[src[e]] + b)
// ---------------------------------------------------------------------------
__global__ __launch_bounds__(256) void gather_nodes(const float* __restrict__ h,
                                                    const int* __restrict__ srcsorted,
                                                    const int* __restrict__ offs,
                                                    const int* __restrict__ deg,
                                                    const float* __restrict__ x,
                                                    const float* __restrict__ b,
                                                    float* __restrict__ out,
                                                    int n_nodes) {
    const int gid = blockIdx.x * 256 + threadIdx.x;
    const int node = gid >> 6;
    if (node >= n_nodes) return;
    const int lane = threadIdx.x & 63;
    const int c = lane * 2;

    const int start = offs[node];
    const int cnt = deg[node];

    float2 acc = make_float2(0.f, 0.f);
    int j = 0;
    for (; j + 4 <= cnt; j += 4) {
        const int s0 = srcsorted[start + j + 0];
        const int s1 = srcsorted[start + j + 1];
        const int s2 = srcsorted[start + j + 2];
        const int s3 = srcsorted[start + j + 3];
        const float2 a0 = *(const float2*)(h + (size_t)s0 * NDIM + c);
        const float2 a1 = *(const float2*)(h + (size_t)s1 * NDIM + c);
        const float2 a2 = *(const float2*)(h + (size_t)s2 * NDIM + c);
        const float2 a3 = *(const float2*)(h + (size_t)s3 * NDIM + c);
        acc.x += (a0.x + a1.x) + (a2.x + a3.x);
        acc.y += (a0.y + a1.y) + (a2.y + a3.y);
    }
    for (; j < cnt; ++j) {
        const int s0 = srcsorted[start + j];
        const float2 a0 = *(const float2*)(h + (size_t)s0 * NDIM + c);
        acc.x += a0.x;
        acc.y += a0.y;
    }

    const float2 xv = *(const float2*)(x + (size_t)node * NDIM + c);
    const float2 bv = *(const float2*)(b + c);
    float2 r;
    r.x = xv.x + fmaxf(acc.x + bv.x, 0.f);
    r.y = xv.y + fmaxf(acc.y + bv.y, 0.f);
    *(float2*)(out + (size_t)node * NDIM + c) = r;
}

// ---------------------------------------------------------------------------
// Fallback (only if ws_size is too small for CSR): atomic scatter path
// ---------------------------------------------------------------------------
__global__ __launch_bounds__(256) void scatter_add(const float* __restrict__ h,
                                                   const int* __restrict__ src,
                                                   const int* __restrict__ dst,
                                                   float* __restrict__ agg,
                                                   int n_edges) {
    const int gid = blockIdx.x * 256 + threadIdx.x;
    const int e = gid >> 5;
    if (e >= n_edges) return;
    const int q = (gid & 31) * 4;
    const int s = src[e];
    const int d = dst[e];
    float4 v = *(const float4*)(h + (size_t)s * NDIM + q);
    float* ap = agg + (size_t)d * NDIM + q;
    atomicAdd(ap + 0, v.x);
    atomicAdd(ap + 1, v.y);
    atomicAdd(ap + 2, v.z);
    atomicAdd(ap + 3, v.w);
}

__global__ __launch_bounds__(256) void finalize(const float* __restrict__ x,
                                                const float* __restrict__ b,
                                                float* __restrict__ out,
                                                int n_vec4) {
    const int i = blockIdx.x * 256 + threadIdx.x;
    if (i >= n_vec4) return;
    float4 xv = ((const float4*)x)[i];
    float4 av = ((float4*)out)[i];
    const int dcol = (i * 4) & (NDIM - 1);
    float4 bv = *(const float4*)(b + dcol);
    float4 r;
    r.x = xv.x + fmaxf(av.x + bv.x, 0.f);
    r.y = xv.y + fmaxf(av.y + bv.y, 0.f);
    r.z = xv.z + fmaxf(av.z + bv.z, 0.f);
    r.w = xv.w + fmaxf(av.w + bv.w, 0.f);
    ((float4*)out)[i] = r;
}

extern "C" void kernel_launch(void* const* d_in, const int* in_sizes, int n_in,
                              void* d_out, int out_size, void* d_ws, size_t ws_size,
                              hipStream_t stream) {
    const float* x    = (const float*)d_in[0];
    const int*   esrc = (const int*)d_in[1];
    const int*   edst = (const int*)d_in[2];
    const float* W    = (const float*)d_in[3];
    const float* b    = (const float*)d_in[4];
    float* out = (float*)d_out;

    const int n_nodes = in_sizes[0] / NDIM;
    const int n_edges = in_sizes[1];

    // Workspace layout
    float* h = (float*)d_ws;                       // N*128 f32
    int* deg       = (int*)(h + (size_t)n_nodes * NDIM);  // N
    int* offs      = deg + n_nodes;                // N
    int* cursor    = offs + n_nodes;               // N
    int* partials  = cursor + n_nodes;             // up to 1024
    int* srcsorted = partials + 1024;              // E

    const size_t required = (size_t)n_nodes * NDIM * 4 +
                            (size_t)(3 * n_nodes + 1024 + n_edges) * 4;

    // h = x @ W (needed by both paths)
    gemm128<<<(n_nodes + 15) / 16, 256, 0, stream>>>(x, W, h, n_nodes);

    if (ws_size >= required) {
        // ---- CSR path (no float atomics) ----
        hipMemsetAsync(deg, 0, (size_t)n_nodes * sizeof(int), stream);
        hist_dst<<<(n_edges + 255) / 256, 256, 0, stream>>>(edst, deg, n_edges);

        const int nchunks = (n_nodes + 1023) / 1024;
        scan_chunks<<<nchunks, 256, 0, stream>>>(deg, offs, partials, n_nodes);
        scan_partials<<<1, 64, 0, stream>>>(partials, nchunks);
        add_base<<<(n_nodes + 255) / 256, 256, 0, stream>>>(offs, partials, cursor, n_nodes);

        bucket_fill<<<(n_edges + 255) / 256, 256, 0, stream>>>(esrc, edst, cursor, srcsorted, n_edges);

        const long long gthreads = (long long)n_nodes * 64;
        gather_nodes<<<(int)((gthreads + 255) / 256), 256, 0, stream>>>(
            h, srcsorted, offs, deg, x, b, out, n_nodes);
    } else {
        // ---- fallback: atomic scatter ----
        hipMemsetAsync(d_out, 0, (size_t)out_size * sizeof(float), stream);
        const long long scatter_threads = (long long)n_edges * 32;
        scatter_add<<<(int)((scatter_threads + 255) / 256), 256, 0, stream>>>(h, esrc, edst, out, n_edges);
        const int n_vec4 = n_nodes * NDIM / 4;
        finalize<<<(n_vec4 + 255) / 256, 256, 0, stream>>>(x, b, out, n_vec4);
    }
}

// Round 3
// 389.733 us; speedup vs baseline: 7.2477x; 1.1295x over previous
//
#include <hip/hip_runtime.h>

#define NDIM 128

typedef __attribute__((ext_vector_type(8))) short short8;
typedef __attribute__((ext_vector_type(4))) float f32x4;

__device__ inline unsigned short f2bf_rne(float f) {
    unsigned int u = __float_as_uint(f);
    unsigned int r = u + 0x7fffu + ((u >> 16) & 1u);
    return (unsigned short)(r >> 16);
}
__device__ inline float bf2f(unsigned short s) {
    return __uint_as_float(((unsigned int)s) << 16);
}

// ---------------------------------------------------------------------------
// Kernel 1: h = x @ W via bf16 MFMA with split-precision correction:
//   h ~= xh@Wh + xh@Wl + xl@Wh   (error ~2^-17 relative)
// W staged in LDS transposed as bf16 hi/lo (2 x 32 KB), XOR k-swizzle so the
// B-fragment ds_read_b128 is ~2-way conflict-free.
// Block = 256 thr = 4 waves; 16 rows/wave -> 64 rows/block.
// mfma_f32_16x16x32_bf16: A[row=lane&15][k=(lane>>4)*8+j],
//                         B[k=(lane>>4)*8+j][col=lane&15],
//                         C[col=lane&15][row=(lane>>4)*4+reg]  (m89/m91)
// ---------------------------------------------------------------------------
__global__ __launch_bounds__(256) void gemm128_mfma(const float* __restrict__ x,
                                                    const float* __restrict__ W,
                                                    float* __restrict__ h,
                                                    int n_nodes) {
    __shared__ __align__(16) unsigned short Wt[2][NDIM * NDIM];  // 64 KB
    const int tid = threadIdx.x;

    // Stage W: read fp32 row-major [k][col], write bf16 hi/lo transposed+swizzled.
    const float4* W4 = (const float4*)W;
#pragma unroll
    for (int i = 0; i < 16; ++i) {
        const int vid = i * 256 + tid;      // 0..4095
        const int k = vid >> 5;             // W row
        const int c4 = (vid & 31) * 4;      // col base
        const float4 w = W4[vid];
        const float* wf = (const float*)&w;
#pragma unroll
        for (int j = 0; j < 4; ++j) {
            const int col = c4 + j;
            const unsigned short hi = f2bf_rne(wf[j]);
            const unsigned short lo = f2bf_rne(wf[j] - bf2f(hi));
            const int ksw = k ^ ((col & 7) << 3);
            Wt[0][col * NDIM + ksw] = hi;
            Wt[1][col * NDIM + ksw] = lo;
        }
    }
    __syncthreads();

    const int wave = tid >> 6;
    const int lane = tid & 63;
    const int lc = lane & 15;
    const int kq = (lane >> 4) * 8;
    const int row0 = blockIdx.x * 64 + wave * 16;

    // A-operand row for this lane (clamped for tail blocks)
    int arow = row0 + lc;
    arow = (arow < n_nodes) ? arow : (n_nodes - 1);
    const float* xr = x + (size_t)arow * NDIM;

    f32x4 acc[8];
#pragma unroll
    for (int t = 0; t < 8; ++t) acc[t] = (f32x4){0.f, 0.f, 0.f, 0.f};

#pragma unroll
    for (int ks = 0; ks < 4; ++ks) {
        const int kbase = ks * 32 + kq;
        const float4 v0 = *(const float4*)(xr + kbase);
        const float4 v1 = *(const float4*)(xr + kbase + 4);
        const float* vf0 = (const float*)&v0;
        const float* vf1 = (const float*)&v1;

        short8 ah, al;
#pragma unroll
        for (int j = 0; j < 4; ++j) {
            unsigned short hi = f2bf_rne(vf0[j]);
            ah[j] = (short)hi;
            al[j] = (short)f2bf_rne(vf0[j] - bf2f(hi));
            hi = f2bf_rne(vf1[j]);
            ah[j + 4] = (short)hi;
            al[j + 4] = (short)f2bf_rne(vf1[j] - bf2f(hi));
        }

#pragma unroll
        for (int t = 0; t < 8; ++t) {
            const int col = t * 16 + lc;
            const int ksw = kbase ^ ((col & 7) << 3);
            const short8 bh = *(const short8*)&Wt[0][col * NDIM + ksw];
            const short8 bl = *(const short8*)&Wt[1][col * NDIM + ksw];
            acc[t] = __builtin_amdgcn_mfma_f32_16x16x32_bf16(ah, bh, acc[t], 0, 0, 0);
            acc[t] = __builtin_amdgcn_mfma_f32_16x16x32_bf16(ah, bl, acc[t], 0, 0, 0);
            acc[t] = __builtin_amdgcn_mfma_f32_16x16x32_bf16(al, bh, acc[t], 0, 0, 0);
        }
    }

    const int orow0 = row0 + (lane >> 4) * 4;
#pragma unroll
    for (int t = 0; t < 8; ++t) {
#pragma unroll
        for (int r = 0; r < 4; ++r) {
            const int row = orow0 + r;
            if (row < n_nodes) {
                h[(size_t)row * NDIM + t * 16 + lc] = acc[t][r];
            }
        }
    }
}

// ---------------------------------------------------------------------------
// CSR construction: histogram -> chunked exclusive scan -> bucket fill
// ---------------------------------------------------------------------------
__global__ __launch_bounds__(256) void hist_dst(const int* __restrict__ dst,
                                                int* __restrict__ deg,
                                                int n_edges) {
    const int e = blockIdx.x * 256 + threadIdx.x;
    if (e >= n_edges) return;
    atomicAdd(&deg[dst[e]], 1);
}

__global__ __launch_bounds__(256) void scan_chunks(const int* __restrict__ deg,
                                                   int* __restrict__ offs,
                                                   int* __restrict__ partials,
                                                   int n) {
    __shared__ int sums[256];
    const int t = threadIdx.x;
    const int base = blockIdx.x * 1024;

    int v[4];
    int tot = 0;
#pragma unroll
    for (int j = 0; j < 4; ++j) {
        const int idx = base + t * 4 + j;
        v[j] = (idx < n) ? deg[idx] : 0;
        tot += v[j];
    }
    sums[t] = tot;
    __syncthreads();

    for (int off = 1; off < 256; off <<= 1) {
        const int tmp = (t >= off) ? sums[t - off] : 0;
        __syncthreads();
        sums[t] += tmp;
        __syncthreads();
    }

    int run = (t > 0) ? sums[t - 1] : 0;
#pragma unroll
    for (int j = 0; j < 4; ++j) {
        const int idx = base + t * 4 + j;
        if (idx < n) offs[idx] = run;
        run += v[j];
    }
    if (t == 255) partials[blockIdx.x] = sums[255];
}

__global__ void scan_partials(int* partials, int nchunks) {
    if (threadIdx.x == 0 && blockIdx.x == 0) {
        int run = 0;
        for (int i = 0; i < nchunks; ++i) {
            const int v = partials[i];
            partials[i] = run;
            run += v;
        }
    }
}

__global__ __launch_bounds__(256) void add_base(int* __restrict__ offs,
                                                const int* __restrict__ partials,
                                                int* __restrict__ cursor,
                                                int n) {
    const int i = blockIdx.x * 256 + threadIdx.x;
    if (i >= n) return;
    const int o = offs[i] + partials[i >> 10];
    offs[i] = o;
    cursor[i] = o;
}

__global__ __launch_bounds__(256) void bucket_fill(const int* __restrict__ src,
                                                   const int* __restrict__ dst,
                                                   int* __restrict__ cursor,
                                                   int* __restrict__ srcsorted,
                                                   int n_edges) {
    const int e = blockIdx.x * 256 + threadIdx.x;
    if (e >= n_edges) return;
    const int pos = atomicAdd(&cursor[dst[e]], 1);
    srcsorted[pos] = src[e];
}

// ---------------------------------------------------------------------------
// Gather + epilogue: one wave per node; lane owns 2 cols (float2).
// out[n] = x[n] + relu(sum_{e in CSR[n]} h[src[e]] + b)
// ---------------------------------------------------------------------------
__global__ __launch_bounds__(256) void gather_nodes(const float* __restrict__ h,
                                                    const int* __restrict__ srcsorted,
                                                    const int* __restrict__ offs,
                                                    const int* __restrict__ deg,
                                                    const float* __restrict__ x,
                                                    const float* __restrict__ b,
                                                    float* __restrict__ out,
                                                    int n_nodes) {
    const int gid = blockIdx.x * 256 + threadIdx.x;
    const int node = gid >> 6;
    if (node >= n_nodes) return;
    const int lane = threadIdx.x & 63;
    const int c = lane * 2;

    const int start = offs[node];
    const int cnt = deg[node];

    float2 acc = make_float2(0.f, 0.f);
    int j = 0;
    for (; j + 4 <= cnt; j += 4) {
        const int s0 = srcsorted[start + j + 0];
        const int s1 = srcsorted[start + j + 1];
        const int s2 = srcsorted[start + j + 2];
        const int s3 = srcsorted[start + j + 3];
        const float2 a0 = *(const float2*)(h + (size_t)s0 * NDIM + c);
        const float2 a1 = *(const float2*)(h + (size_t)s1 * NDIM + c);
        const float2 a2 = *(const float2*)(h + (size_t)s2 * NDIM + c);
        const float2 a3 = *(const float2*)(h + (size_t)s3 * NDIM + c);
        acc.x += (a0.x + a1.x) + (a2.x + a3.x);
        acc.y += (a0.y + a1.y) + (a2.y + a3.y);
    }
    for (; j < cnt; ++j) {
        const int s0 = srcsorted[start + j];
        const float2 a0 = *(const float2*)(h + (size_t)s0 * NDIM + c);
        acc.x += a0.x;
        acc.y += a0.y;
    }

    const float2 xv = *(const float2*)(x + (size_t)node * NDIM + c);
    const float2 bv = *(const float2*)(b + c);
    float2 r;
    r.x = xv.x + fmaxf(acc.x + bv.x, 0.f);
    r.y = xv.y + fmaxf(acc.y + bv.y, 0.f);
    *(float2*)(out + (size_t)node * NDIM + c) = r;
}

// ---------------------------------------------------------------------------
// Fallback (only if ws_size is too small for CSR): atomic scatter path
// ---------------------------------------------------------------------------
__global__ __launch_bounds__(256) void scatter_add(const float* __restrict__ h,
                                                   const int* __restrict__ src,
                                                   const int* __restrict__ dst,
                                                   float* __restrict__ agg,
                                                   int n_edges) {
    const int gid = blockIdx.x * 256 + threadIdx.x;
    const int e = gid >> 5;
    if (e >= n_edges) return;
    const int q = (gid & 31) * 4;
    const int s = src[e];
    const int d = dst[e];
    float4 v = *(const float4*)(h + (size_t)s * NDIM + q);
    float* ap = agg + (size_t)d * NDIM + q;
    atomicAdd(ap + 0, v.x);
    atomicAdd(ap + 1, v.y);
    atomicAdd(ap + 2, v.z);
    atomicAdd(ap + 3, v.w);
}

__global__ __launch_bounds__(256) void finalize(const float* __restrict__ x,
                                                const float* __restrict__ b,
                                                float* __restrict__ out,
                                                int n_vec4) {
    const int i = blockIdx.x * 256 + threadIdx.x;
    if (i >= n_vec4) return;
    float4 xv = ((const float4*)x)[i];
    float4 av = ((float4*)out)[i];
    const int dcol = (i * 4) & (NDIM - 1);
    float4 bv = *(const float4*)(b + dcol);
    float4 r;
    r.x = xv.x + fmaxf(av.x + bv.x, 0.f);
    r.y = xv.y + fmaxf(av.y + bv.y, 0.f);
    r.z = xv.z + fmaxf(av.z + bv.z, 0.f);
    r.w = xv.w + fmaxf(av.w + bv.w, 0.f);
    ((float4*)out)[i] = r;
}

extern "C" void kernel_launch(void* const* d_in, const int* in_sizes, int n_in,
                              void* d_out, int out_size, void* d_ws, size_t ws_size,
                              hipStream_t stream) {
    const float* x    = (const float*)d_in[0];
    const int*   esrc = (const int*)d_in[1];
    const int*   edst = (const int*)d_in[2];
    const float* W    = (const float*)d_in[3];
    const float* b    = (const float*)d_in[4];
    float* out = (float*)d_out;

    const int n_nodes = in_sizes[0] / NDIM;
    const int n_edges = in_sizes[1];

    // Workspace layout
    float* h = (float*)d_ws;                              // N*128 f32
    int* deg       = (int*)(h + (size_t)n_nodes * NDIM);  // N
    int* offs      = deg + n_nodes;                       // N
    int* cursor    = offs + n_nodes;                      // N
    int* partials  = cursor + n_nodes;                    // up to 1024
    int* srcsorted = partials + 1024;                     // E

    const size_t required = (size_t)n_nodes * NDIM * 4 +
                            (size_t)(3 * n_nodes + 1024 + n_edges) * 4;

    // h = x @ W (bf16-split MFMA, ~fp32 accuracy)
    gemm128_mfma<<<(n_nodes + 63) / 64, 256, 0, stream>>>(x, W, h, n_nodes);

    if (ws_size >= required) {
        // ---- CSR path (no float atomics) ----
        hipMemsetAsync(deg, 0, (size_t)n_nodes * sizeof(int), stream);
        hist_dst<<<(n_edges + 255) / 256, 256, 0, stream>>>(edst, deg, n_edges);

        const int nchunks = (n_nodes + 1023) / 1024;
        scan_chunks<<<nchunks, 256, 0, stream>>>(deg, offs, partials, n_nodes);
        scan_partials<<<1, 64, 0, stream>>>(partials, nchunks);
        add_base<<<(n_nodes + 255) / 256, 256, 0, stream>>>(offs, partials, cursor, n_nodes);

        bucket_fill<<<(n_edges + 255) / 256, 256, 0, stream>>>(esrc, edst, cursor, srcsorted, n_edges);

        const long long gthreads = (long long)n_nodes * 64;
        gather_nodes<<<(int)((gthreads + 255) / 256), 256, 0, stream>>>(
            h, srcsorted, offs, deg, x, b, out, n_nodes);
    } else {
        // ---- fallback: atomic scatter ----
        hipMemsetAsync(d_out, 0, (size_t)out_size * sizeof(float), stream);
        const long long scatter_threads = (long long)n_edges * 32;
        scatter_add<<<(int)((scatter_threads + 255) / 256), 256, 0, stream>>>(h, esrc, edst, out, n_edges);
        const int n_vec4 = n_nodes * NDIM / 4;
        finalize<<<(n_vec4 + 255) / 256, 256, 0, stream>>>(x, b, out, n_vec4);
    }
}

// Round 4
// 191.057 us; speedup vs baseline: 14.7845x; 2.0399x over previous
//
#include <hip/hip_runtime.h>

#define NDIM 128
#define BIN_SHIFT 8
#define BIN_NODES 256          // 1 << BIN_SHIFT
#define MAX_BINS 512           // supports up to 131072 nodes
#define TILE 4096              // edges per bin_scatter block
#define CSR_CAP 6144           // per-bin LDS capacity in csr_fill (E/bin ~ 4090)

typedef __attribute__((ext_vector_type(8))) short short8;
typedef __attribute__((ext_vector_type(4))) float f32x4;

__device__ inline unsigned short f2bf_rne(float f) {
    unsigned int u = __float_as_uint(f);
    unsigned int r = u + 0x7fffu + ((u >> 16) & 1u);
    return (unsigned short)(r >> 16);
}
__device__ inline float bf2f(unsigned short s) {
    return __uint_as_float(((unsigned int)s) << 16);
}
__device__ inline float bf_lo(unsigned int u) { return __uint_as_float(u << 16); }
__device__ inline float bf_hi(unsigned int u) { return __uint_as_float(u & 0xffff0000u); }

// ---------------------------------------------------------------------------
// Kernel 1: h = x @ W via bf16-split MFMA (h ~= xh@Wh + xh@Wl + xl@Wh).
// h stored as bf16. Grid-stride over 64-row tiles; W staged once per block.
// mfma_f32_16x16x32_bf16: A[row=lane&15][k=(lane>>4)*8+j],
//                         B[k][col=lane&15], C[col=lane&15][row=(lane>>4)*4+r]
// ---------------------------------------------------------------------------
__global__ __launch_bounds__(256) void gemm128_mfma(const float* __restrict__ x,
                                                    const float* __restrict__ W,
                                                    unsigned short* __restrict__ h,
                                                    int n_nodes, int ntiles) {
    __shared__ __align__(16) unsigned short Wt[2][NDIM * NDIM];  // 64 KB
    const int tid = threadIdx.x;

    const float4* W4 = (const float4*)W;
#pragma unroll
    for (int i = 0; i < 16; ++i) {
        const int vid = i * 256 + tid;
        const int k = vid >> 5;
        const int c4 = (vid & 31) * 4;
        const float4 w = W4[vid];
        const float* wf = (const float*)&w;
#pragma unroll
        for (int j = 0; j < 4; ++j) {
            const int col = c4 + j;
            const unsigned short hi = f2bf_rne(wf[j]);
            const unsigned short lo = f2bf_rne(wf[j] - bf2f(hi));
            const int ksw = k ^ ((col & 7) << 3);
            Wt[0][col * NDIM + ksw] = hi;
            Wt[1][col * NDIM + ksw] = lo;
        }
    }
    __syncthreads();

    const int wave = tid >> 6;
    const int lane = tid & 63;
    const int lc = lane & 15;
    const int kq = (lane >> 4) * 8;

    for (int tile = blockIdx.x; tile < ntiles; tile += gridDim.x) {
        const int row0 = tile * 64 + wave * 16;

        int arow = row0 + lc;
        arow = (arow < n_nodes) ? arow : (n_nodes - 1);
        const float* xr = x + (size_t)arow * NDIM;

        f32x4 acc[8];
#pragma unroll
        for (int t = 0; t < 8; ++t) acc[t] = (f32x4){0.f, 0.f, 0.f, 0.f};

#pragma unroll
        for (int ks = 0; ks < 4; ++ks) {
            const int kbase = ks * 32 + kq;
            const float4 v0 = *(const float4*)(xr + kbase);
            const float4 v1 = *(const float4*)(xr + kbase + 4);
            const float* vf0 = (const float*)&v0;
            const float* vf1 = (const float*)&v1;

            short8 ah, al;
#pragma unroll
            for (int j = 0; j < 4; ++j) {
                unsigned short hi = f2bf_rne(vf0[j]);
                ah[j] = (short)hi;
                al[j] = (short)f2bf_rne(vf0[j] - bf2f(hi));
                hi = f2bf_rne(vf1[j]);
                ah[j + 4] = (short)hi;
                al[j + 4] = (short)f2bf_rne(vf1[j] - bf2f(hi));
            }

#pragma unroll
            for (int t = 0; t < 8; ++t) {
                const int col = t * 16 + lc;
                const int ksw = kbase ^ ((col & 7) << 3);
                const short8 bh = *(const short8*)&Wt[0][col * NDIM + ksw];
                const short8 bl = *(const short8*)&Wt[1][col * NDIM + ksw];
                acc[t] = __builtin_amdgcn_mfma_f32_16x16x32_bf16(ah, bh, acc[t], 0, 0, 0);
                acc[t] = __builtin_amdgcn_mfma_f32_16x16x32_bf16(ah, bl, acc[t], 0, 0, 0);
                acc[t] = __builtin_amdgcn_mfma_f32_16x16x32_bf16(al, bh, acc[t], 0, 0, 0);
            }
        }

        const int orow0 = row0 + (lane >> 4) * 4;
#pragma unroll
        for (int t = 0; t < 8; ++t) {
#pragma unroll
            for (int r = 0; r < 4; ++r) {
                const int row = orow0 + r;
                if (row < n_nodes) {
                    h[(size_t)row * NDIM + t * 16 + lc] = f2bf_rne(acc[t][r]);
                }
            }
        }
    }
}

// ---------------------------------------------------------------------------
// bin_hist: global histogram over 256-node bins (dst >> 8), LDS-staged.
// ---------------------------------------------------------------------------
__global__ __launch_bounds__(256) void bin_hist(const int* __restrict__ dst,
                                                int* __restrict__ binCount,
                                                int n_edges, int nb) {
    __shared__ int lh[MAX_BINS];
    const int tid = threadIdx.x;
    for (int i = tid; i < nb; i += 256) lh[i] = 0;
    __syncthreads();
    for (int e = blockIdx.x * 256 + tid; e < n_edges; e += gridDim.x * 256) {
        atomicAdd(&lh[dst[e] >> BIN_SHIFT], 1);
    }
    __syncthreads();
    for (int i = tid; i < nb; i += 256) {
        const int c = lh[i];
        if (c) atomicAdd(&binCount[i], c);
    }
}

// ---------------------------------------------------------------------------
// scan_bins: single block; binBase = exclusive scan of binCount (nb+1 entries),
// binCursor initialized to binBase.
// ---------------------------------------------------------------------------
__global__ __launch_bounds__(256) void scan_bins(const int* __restrict__ binCount,
                                                 int* __restrict__ binBase,
                                                 int* __restrict__ binCursor,
                                                 int nb) {
    __shared__ int v[MAX_BINS];
    __shared__ int sums[256];
    const int t = threadIdx.x;
    v[t] = (t < nb) ? binCount[t] : 0;
    v[t + 256] = (t + 256 < nb) ? binCount[t + 256] : 0;
    __syncthreads();
    const int a = v[2 * t], b = v[2 * t + 1];
    sums[t] = a + b;
    __syncthreads();
    for (int off = 1; off < 256; off <<= 1) {
        const int tmp = (t >= off) ? sums[t - off] : 0;
        __syncthreads();
        sums[t] += tmp;
        __syncthreads();
    }
    const int ex = (t > 0) ? sums[t - 1] : 0;
    if (2 * t < nb)     { binBase[2 * t] = ex;         binCursor[2 * t] = ex; }
    if (2 * t + 1 < nb) { binBase[2 * t + 1] = ex + a; binCursor[2 * t + 1] = ex + a; }
    if (t == 255) binBase[nb] = sums[255];
}

// ---------------------------------------------------------------------------
// bin_scatter (pass 1): tile of TILE edges per block; LDS-sort by bin; reserve
// contiguous per-(block,bin) runs in binCursor; write packed (dstLow<<24|src).
// ---------------------------------------------------------------------------
__global__ __launch_bounds__(256) void bin_scatter(const int* __restrict__ src,
                                                   const int* __restrict__ dst,
                                                   int* __restrict__ binCursor,
                                                   unsigned int* __restrict__ binned,
                                                   int n_edges, int nb) {
    __shared__ int lhist[MAX_BINS];
    __shared__ int lstart[MAX_BINS];
    __shared__ int lcur[MAX_BINS];
    __shared__ int lsums[256];
    __shared__ unsigned int lsorted[TILE];
    const int tid = threadIdx.x;
    const int base = blockIdx.x * TILE;
    const int count = min(TILE, n_edges - base);

    for (int i = tid; i < MAX_BINS; i += 256) lhist[i] = 0;
    __syncthreads();

    int mybin[16];
    unsigned int mypacked[16];
#pragma unroll
    for (int j = 0; j < 16; ++j) {
        const int idx = tid + j * 256;  // coalesced
        if (idx < count) {
            const int d = dst[base + idx];
            const int s = src[base + idx];
            mybin[j] = d >> BIN_SHIFT;
            mypacked[j] = ((unsigned int)(d & (BIN_NODES - 1)) << 24) | (unsigned int)s;
            atomicAdd(&lhist[mybin[j]], 1);
        } else {
            mybin[j] = -1;
            mypacked[j] = 0;
        }
    }
    __syncthreads();

    // exclusive scan of lhist[0..nb) (padded with zeros to MAX_BINS)
    const int a = lhist[2 * tid], b = lhist[2 * tid + 1];
    lsums[tid] = a + b;
    __syncthreads();
    for (int off = 1; off < 256; off <<= 1) {
        const int tmp = (tid >= off) ? lsums[tid - off] : 0;
        __syncthreads();
        lsums[tid] += tmp;
        __syncthreads();
    }
    const int ex = (tid > 0) ? lsums[tid - 1] : 0;
    lstart[2 * tid] = ex;
    lstart[2 * tid + 1] = ex + a;
    lcur[2 * tid] = ex;
    lcur[2 * tid + 1] = ex + a;
    __syncthreads();

    // LDS scatter into bin-sorted order
#pragma unroll
    for (int j = 0; j < 16; ++j) {
        if (mybin[j] >= 0) {
            const int pos = atomicAdd(&lcur[mybin[j]], 1);
            lsorted[pos] = mypacked[j];
        }
    }
    __syncthreads();

    // reserve global runs per bin (reuse lcur for global bases)
    for (int i = tid; i < nb; i += 256) {
        const int c = lhist[i];
        lcur[i] = c ? atomicAdd(&binCursor[i], c) : 0;
    }
    __syncthreads();

    // coalesced-ish write-out; bin of position p via binary search in lstart
    for (int p = tid; p < count; p += 256) {
        int lo = 0, hi = nb - 1;
        while (lo < hi) {
            const int mid = (lo + hi + 1) >> 1;
            if (lstart[mid] <= p) lo = mid; else hi = mid - 1;
        }
        binned[lcur[lo] + (p - lstart[lo])] = lsorted[p];
    }
}

// ---------------------------------------------------------------------------
// csr_fill (pass 2): one block per bin. Local hist -> scan -> LDS scatter ->
// coalesced stream-out of srcsorted; also writes deg[] and offs[].
// ---------------------------------------------------------------------------
__global__ __launch_bounds__(256) void csr_fill(const unsigned int* __restrict__ binned,
                                                const int* __restrict__ binBase,
                                                int* __restrict__ deg,
                                                int* __restrict__ offs,
                                                int* __restrict__ srcsorted,
                                                int n_nodes) {
    __shared__ int lhist[BIN_NODES];
    __shared__ int lscan[BIN_NODES];
    __shared__ int lcur[BIN_NODES];
    __shared__ unsigned int lin[CSR_CAP];
    __shared__ int lout[CSR_CAP];
    const int b = blockIdx.x;
    const int tid = threadIdx.x;
    const int gbase = binBase[b];
    const int count = binBase[b + 1] - gbase;
    const int node0 = b * BIN_NODES;

    lhist[tid] = 0;
    __syncthreads();

    const bool fits = (count <= CSR_CAP);

    if (fits) {
        for (int p = tid; p < count; p += 256) {
            const unsigned int v = binned[gbase + p];
            lin[p] = v;
            atomicAdd(&lhist[v >> 24], 1);
        }
    } else {
        for (int p = tid; p < count; p += 256) {
            atomicAdd(&lhist[binned[gbase + p] >> 24], 1);
        }
    }
    __syncthreads();

    // exclusive scan of lhist[256]
    const int myv = lhist[tid];
    lscan[tid] = myv;
    __syncthreads();
    for (int off = 1; off < 256; off <<= 1) {
        const int tmp = (tid >= off) ? lscan[tid - off] : 0;
        __syncthreads();
        lscan[tid] += tmp;
        __syncthreads();
    }
    const int ex = lscan[tid] - myv;

    const int node = node0 + tid;
    if (node < n_nodes) {
        deg[node] = myv;
        offs[node] = gbase + ex;
    }
    lcur[tid] = ex;
    __syncthreads();

    if (fits) {
        for (int p = tid; p < count; p += 256) {
            const unsigned int v = lin[p];
            const int pos = atomicAdd(&lcur[v >> 24], 1);
            lout[pos] = (int)(v & 0xFFFFFFu);
        }
        __syncthreads();
        for (int p = tid; p < count; p += 256) {
            srcsorted[gbase + p] = lout[p];
        }
    } else {
        // pathological bin: direct (uncoalesced) placement, still correct
        for (int p = tid; p < count; p += 256) {
            const unsigned int v = binned[gbase + p];
            const int pos = atomicAdd(&lcur[v >> 24], 1);
            srcsorted[gbase + pos] = (int)(v & 0xFFFFFFu);
        }
    }
}

// ---------------------------------------------------------------------------
// Gather + epilogue: one wave per node; lane owns 2 cols; h is bf16.
// out[n] = x[n] + relu(sum_{e in CSR[n]} h[src[e]] + b)
// ---------------------------------------------------------------------------
__global__ __launch_bounds__(256) void gather_nodes(const unsigned short* __restrict__ h,
                                                    const int* __restrict__ srcsorted,
                                                    const int* __restrict__ offs,
                                                    const int* __restrict__ deg,
                                                    const float* __restrict__ x,
                                                    const float* __restrict__ b,
                                                    float* __restrict__ out,
                                                    int n_nodes) {
    const int gid = blockIdx.x * 256 + threadIdx.x;
    const int node = gid >> 6;
    if (node >= n_nodes) return;
    const int lane = threadIdx.x & 63;
    const int c = lane * 2;

    const int start = offs[node];
    const int cnt = deg[node];

    float accx = 0.f, accy = 0.f;
    int j = 0;
    for (; j + 4 <= cnt; j += 4) {
        const int s0 = srcsorted[start + j + 0];
        const int s1 = srcsorted[start + j + 1];
        const int s2 = srcsorted[start + j + 2];
        const int s3 = srcsorted[start + j + 3];
        const unsigned int a0 = *(const unsigned int*)(h + (size_t)s0 * NDIM + c);
        const unsigned int a1 = *(const unsigned int*)(h + (size_t)s1 * NDIM + c);
        const unsigned int a2 = *(const unsigned int*)(h + (size_t)s2 * NDIM + c);
        const unsigned int a3 = *(const unsigned int*)(h + (size_t)s3 * NDIM + c);
        accx += (bf_lo(a0) + bf_lo(a1)) + (bf_lo(a2) + bf_lo(a3));
        accy += (bf_hi(a0) + bf_hi(a1)) + (bf_hi(a2) + bf_hi(a3));
    }
    for (; j < cnt; ++j) {
        const int s0 = srcsorted[start + j];
        const unsigned int a0 = *(const unsigned int*)(h + (size_t)s0 * NDIM + c);
        accx += bf_lo(a0);
        accy += bf_hi(a0);
    }

    const float2 xv = *(const float2*)(x + (size_t)node * NDIM + c);
    const float2 bv = *(const float2*)(b + c);
    float2 r;
    r.x = xv.x + fmaxf(accx + bv.x, 0.f);
    r.y = xv.y + fmaxf(accy + bv.y, 0.f);
    *(float2*)(out + (size_t)node * NDIM + c) = r;
}

// ---------------------------------------------------------------------------
// Fallback (never expected): atomic scatter from bf16 h.
// ---------------------------------------------------------------------------
__global__ __launch_bounds__(256) void scatter_add_bf(const unsigned short* __restrict__ h,
                                                      const int* __restrict__ src,
                                                      const int* __restrict__ dst,
                                                      float* __restrict__ agg,
                                                      int n_edges) {
    const int gid = blockIdx.x * 256 + threadIdx.x;
    const int e = gid >> 6;
    if (e >= n_edges) return;
    const int c = (gid & 63) * 2;
    const int s = src[e];
    const int d = dst[e];
    const unsigned int v = *(const unsigned int*)(h + (size_t)s * NDIM + c);
    float* ap = agg + (size_t)d * NDIM + c;
    atomicAdd(ap + 0, bf_lo(v));
    atomicAdd(ap + 1, bf_hi(v));
}

__global__ __launch_bounds__(256) void finalize(const float* __restrict__ x,
                                                const float* __restrict__ b,
                                                float* __restrict__ out,
                                                int n_vec4) {
    const int i = blockIdx.x * 256 + threadIdx.x;
    if (i >= n_vec4) return;
    float4 xv = ((const float4*)x)[i];
    float4 av = ((float4*)out)[i];
    const int dcol = (i * 4) & (NDIM - 1);
    float4 bv = *(const float4*)(b + dcol);
    float4 r;
    r.x = xv.x + fmaxf(av.x + bv.x, 0.f);
    r.y = xv.y + fmaxf(av.y + bv.y, 0.f);
    r.z = xv.z + fmaxf(av.z + bv.z, 0.f);
    r.w = xv.w + fmaxf(av.w + bv.w, 0.f);
    ((float4*)out)[i] = r;
}

extern "C" void kernel_launch(void* const* d_in, const int* in_sizes, int n_in,
                              void* d_out, int out_size, void* d_ws, size_t ws_size,
                              hipStream_t stream) {
    const float* x    = (const float*)d_in[0];
    const int*   esrc = (const int*)d_in[1];
    const int*   edst = (const int*)d_in[2];
    const float* W    = (const float*)d_in[3];
    const float* b    = (const float*)d_in[4];
    float* out = (float*)d_out;

    const int n_nodes = in_sizes[0] / NDIM;
    const int n_edges = in_sizes[1];
    const int nb = (n_nodes + BIN_NODES - 1) / BIN_NODES;
    const int ntiles = (n_nodes + 63) / 64;

    // Workspace layout
    unsigned short* h = (unsigned short*)d_ws;                 // N*128 bf16
    int* deg       = (int*)(h + (size_t)n_nodes * NDIM);       // N
    int* offs      = deg + n_nodes;                            // N
    int* binCount  = offs + n_nodes;                           // MAX_BINS
    int* binBase   = binCount + MAX_BINS;                      // MAX_BINS+1
    int* binCursor = binBase + MAX_BINS + 1;                   // MAX_BINS
    unsigned int* binned = (unsigned int*)(binCursor + MAX_BINS);  // E
    int* srcsorted = (int*)(binned + n_edges);                 // E

    const size_t required = (size_t)n_nodes * NDIM * 2 +
                            (size_t)(2 * n_nodes + 3 * MAX_BINS + 1 + 2 * n_edges) * 4;

    // h = x @ W (bf16-split MFMA), grid-stride
    const int gblocks = (ntiles < 512) ? ntiles : 512;
    gemm128_mfma<<<gblocks, 256, 0, stream>>>(x, W, h, n_nodes, ntiles);

    if (nb <= MAX_BINS && ws_size >= required) {
        hipMemsetAsync(binCount, 0, MAX_BINS * sizeof(int), stream);
        bin_hist<<<1024, 256, 0, stream>>>(edst, binCount, n_edges, nb);
        scan_bins<<<1, 256, 0, stream>>>(binCount, binBase, binCursor, nb);
        const int ntile_e = (n_edges + TILE - 1) / TILE;
        bin_scatter<<<ntile_e, 256, 0, stream>>>(esrc, edst, binCursor, binned, n_edges, nb);
        csr_fill<<<nb, 256, 0, stream>>>(binned, binBase, deg, offs, srcsorted, n_nodes);

        const long long gthreads = (long long)n_nodes * 64;
        gather_nodes<<<(int)((gthreads + 255) / 256), 256, 0, stream>>>(
            h, srcsorted, offs, deg, x, b, out, n_nodes);
    } else {
        // fallback: atomic scatter
        hipMemsetAsync(d_out, 0, (size_t)out_size * sizeof(float), stream);
        const long long st = (long long)n_edges * 64;
        scatter_add_bf<<<(int)((st + 255) / 256), 256, 0, stream>>>(h, esrc, edst, out, n_edges);
        const int n_vec4 = n_nodes * NDIM / 4;
        finalize<<<(n_vec4 + 255) / 256, 256, 0, stream>>>(x, b, out, n_vec4);
    }
}